// Round 12
// baseline (251.519 us; speedup 1.0000x reference)
//
#include <hip/hip_runtime.h>
#include <hip/hip_bf16.h>
#include <math.h>

#define B_ 2
#define S_ 2048
#define D_ 1024
#define H_ 16
#define DK_ 64
#define SW_ (S_ / 64)   // 32 packed mask words per row

typedef unsigned short u16;
typedef unsigned int u32;
typedef unsigned long long u64;
typedef __attribute__((ext_vector_type(8))) short short8;
typedef __attribute__((ext_vector_type(4))) float float4_;
typedef __attribute__((ext_vector_type(4))) unsigned int uint4_;

static __device__ inline u16 f_to_bf16(float f) {
    union { float f; u32 i; } x; x.f = f;
    u32 r = x.i + 0x7fff + ((x.i >> 16) & 1);  // RNE
    return (u16)(r >> 16);
}

// two f32 -> packed u32 of two bf16 (RNE), low half = first arg
static __device__ __forceinline__ u32 packrne(float a, float b) {
    union { float f; u32 i; } xa, xb; xa.f = a; xb.f = b;
    u32 lo = (xa.i + 0x7fff + ((xa.i >> 16) & 1)) >> 16;
    u32 hi = (xb.i + 0x7fff + ((xb.i >> 16) & 1)) & 0xffff0000u;
    return lo | hi;
}

// hw packed f32x2 -> bf16x2 (low = a). Single VOP3 vs ~5 int ops.
static __device__ __forceinline__ u32 cvtpk(float a, float b) {
    u32 r;
    asm("v_cvt_pk_bf16_f32 %0, %1, %2" : "=v"(r) : "v"(a), "v"(b));
    return r;
}

static __device__ __forceinline__ float fast_exp2(float x) {
#if __has_builtin(__builtin_amdgcn_exp2f)
    return __builtin_amdgcn_exp2f(x);   // bare v_exp_f32
#else
    return exp2f(x);
#endif
}

// async global->LDS, 16B per lane (wave-uniform base + lane*16).
static __device__ inline void gl_lds16(const u16* g, u16* l) {
    __builtin_amdgcn_global_load_lds((const __attribute__((address_space(1))) void*)g,
                                     (__attribute__((address_space(3))) void*)l, 16, 0, 0);
}

// ---------------- prep: cvt3 (vectorized) | wtrans4 (mpack moved to gemm_qkv) ----------------
__global__ __launch_bounds__(256) void prep(const float* __restrict__ q,
                                            const float* __restrict__ k,
                                            const float* __restrict__ v,
                                            const float* __restrict__ W0,
                                            const float* __restrict__ W1,
                                            const float* __restrict__ W2,
                                            const float* __restrict__ W3,
                                            u16* __restrict__ qb, u16* __restrict__ kb,
                                            u16* __restrict__ vb,
                                            u16* __restrict__ T0, u16* __restrict__ T1,
                                            u16* __restrict__ T2, u16* __restrict__ T3) {
    __shared__ float tile[32][33];
    int gx = blockIdx.x, tid = threadIdx.x;
    if (gx < 6144) {                       // fp32 -> bf16, q/k/v (16B vector store)
        int z = gx >> 11;
        int bx = gx & 2047;
        const float* s = (z == 0) ? q : ((z == 1) ? k : v);
        u16* d = (z == 0) ? qb : ((z == 1) ? kb : vb);
        int i = (bx * 256 + tid) * 8;
        float4_ a0 = *(const float4_*)(s + i);
        float4_ a1 = *(const float4_*)(s + i + 4);
        uint4_ wv_ = { packrne(a0[0], a0[1]), packrne(a0[2], a0[3]),
                       packrne(a1[0], a1[1]), packrne(a1[2], a1[3]) };
        *(uint4_*)(d + i) = wv_;
    } else {                               // W^T x4
        int g2 = gx - 6144;
        int z = g2 >> 10;
        int rem = g2 & 1023;
        const float* W = (z == 0) ? W0 : ((z == 1) ? W1 : ((z == 2) ? W2 : W3));
        u16* Wt = (z == 0) ? T0 : ((z == 1) ? T1 : ((z == 2) ? T2 : T3));
        int k0 = (rem >> 5) * 32, n0 = (rem & 31) * 32;
        int tx = tid & 31, ty = tid >> 5;
        #pragma unroll
        for (int i2 = 0; i2 < 4; ++i2) {
            int row = ty + i2 * 8;
            tile[row][tx] = W[(size_t)(k0 + row) * D_ + n0 + tx];
        }
        __syncthreads();
        #pragma unroll
        for (int i2 = 0; i2 < 4; ++i2) {
            int row = ty + i2 * 8;
            Wt[(size_t)(n0 + row) * D_ + k0 + tx] = f_to_bf16(tile[tx][row]);
        }
    }
}

// ---------------- 128x128x32-step GEMM body, T4 counted-vmcnt dbuf (R5) ----------------
static __device__ __forceinline__ void gemm128_body(u16* lds,
                                                    const u16* __restrict__ A,
                                                    const u16* __restrict__ Bt,
                                                    int K, float4_ (&acc)[4][4]) {
    u16* ldsA = lds;            // 2 bufs x 128*32
    u16* ldsB = lds + 8192;     // 2 bufs x 128*32
    int tm = blockIdx.x, tn = blockIdx.y;
    int t = threadIdx.x, l = t & 63;
    int w = t >> 6, wr = w >> 1, wc = w & 1;
    int colL = l & 15, grp = l >> 4;
    int sw4 = (grp ^ ((colL >> 1) & 3)) << 3;
    int f0 = t, f1 = t + 256;
    int row0 = f0 >> 2, kc0 = (((f0 & 3) ^ ((f0 >> 3) & 3)) << 3);
    int row1 = f1 >> 2, kc1 = (((f1 & 3) ^ ((f1 >> 3) & 3)) << 3);
    const u16* gA0 = A  + (size_t)(tm * 128 + row0) * K + kc0;
    const u16* gA1 = A  + (size_t)(tm * 128 + row1) * K + kc1;
    const u16* gB0 = Bt + (size_t)(tn * 128 + row0) * K + kc0;
    const u16* gB1 = Bt + (size_t)(tn * 128 + row1) * K + kc1;

    #pragma unroll
    for (int mi = 0; mi < 4; ++mi)
        #pragma unroll
        for (int ni = 0; ni < 4; ++ni)
            acc[mi][ni] = (float4_){0.f, 0.f, 0.f, 0.f};

    // prologue: stage k-tile 0 into buf 0
    gl_lds16(gA0, ldsA + f0 * 8);
    gl_lds16(gA1, ldsA + f1 * 8);
    gl_lds16(gB0, ldsB + f0 * 8);
    gl_lds16(gB1, ldsB + f1 * 8);

    for (int k0 = 0; k0 < K; k0 += 32) {
        int cur = (k0 >> 5) & 1;
        if (k0 + 32 < K) {
            int nb = (cur ^ 1) * 4096;
            gl_lds16(gA0 + k0 + 32, ldsA + nb + f0 * 8);
            gl_lds16(gA1 + k0 + 32, ldsA + nb + f1 * 8);
            gl_lds16(gB0 + k0 + 32, ldsB + nb + f0 * 8);
            gl_lds16(gB1 + k0 + 32, ldsB + nb + f1 * 8);
            asm volatile("s_waitcnt vmcnt(4)" ::: "memory");   // tile k0 landed
        } else {
            asm volatile("s_waitcnt vmcnt(0)" ::: "memory");
        }
        __builtin_amdgcn_s_barrier();      // all waves: tile k0 in LDS
        const u16* cA = ldsA + cur * 4096;
        const u16* cB = ldsB + cur * 4096;
        short8 a[4], b[4];
        #pragma unroll
        for (int mi = 0; mi < 4; ++mi)
            a[mi] = *(const short8*)&cA[(wr * 64 + mi * 16 + colL) * 32 + sw4];
        #pragma unroll
        for (int ni = 0; ni < 4; ++ni)
            b[ni] = *(const short8*)&cB[(wc * 64 + ni * 16 + colL) * 32 + sw4];
        #pragma unroll
        for (int mi = 0; mi < 4; ++mi)
            #pragma unroll
            for (int ni = 0; ni < 4; ++ni)
                acc[mi][ni] = __builtin_amdgcn_mfma_f32_16x16x32_bf16(a[mi], b[ni], acc[mi][ni], 0, 0, 0);
        __builtin_amdgcn_s_barrier();      // reads of buf[cur] done (next iter overwrites it)
    }
}

// QKV fused: z = 0/1/2 -> Q/K/V GEMM planes.
// z = 3..18 -> mask bit-pack at FULL width (16 planes x 256 blocks = 4096 blocks,
// 8 independent ballots/wave — R8's regression was 256 blocks x 128 serial rounds;
// this keeps prep-equivalent parallelism while overlapping mask reads with GEMM).
// z==0: Q scaled by 0.125*log2(e). z==2: V scattered to Vt[b][h][dk][tau(s)].
__global__ __launch_bounds__(256, 3) void gemm_qkv(const u16* __restrict__ qb,
                                                   const u16* __restrict__ kb,
                                                   const u16* __restrict__ vb,
                                                   const u16* __restrict__ Wqt,
                                                   const u16* __restrict__ Wkt,
                                                   const u16* __restrict__ Wvt,
                                                   u16* __restrict__ Qp,
                                                   u16* __restrict__ Kp,
                                                   u16* __restrict__ Vt,
                                                   const int* __restrict__ mask,
                                                   u64* __restrict__ mpk) {
    __shared__ u16 lds[16384];
    int z = blockIdx.z;
    int tm = blockIdx.x, tn = blockIdx.y;
    int t = threadIdx.x;

    if (z >= 3) {                          // mask bit-pack, wide (no LDS/barrier use)
        int flat = (z - 3) * 256 + tm * 8 + tn;     // [0, 4096)
        int wv = (flat * 256 + t) >> 6;
        int lane = t & 63;
        #pragma unroll
        for (int i2 = 0; i2 < 8; ++i2) {
            int wd = wv * 8 + i2;
            u64 bits = __ballot(mask[(size_t)wd * 64 + lane] != 0);
            if (lane == 0) mpk[wd] = bits;
        }
        return;
    }

    const u16* A  = (z == 0) ? qb  : ((z == 1) ? kb  : vb);
    const u16* Bt = (z == 0) ? Wqt : ((z == 1) ? Wkt : Wvt);
    float4_ acc[4][4];
    gemm128_body(lds, A, Bt, D_, acc);

    int l = t & 63;
    int w = t >> 6, wr = w >> 1, wc = w & 1;
    int colL = l & 15, grp = l >> 4;

    if (z < 2) {
        u16* Y = (z == 0) ? Qp : Kp;
        float sc = (z == 0) ? (0.125f * 1.44269504f) : 1.0f;
        #pragma unroll
        for (int mi = 0; mi < 4; ++mi)
            #pragma unroll
            for (int ni = 0; ni < 4; ++ni)
                #pragma unroll
                for (int r = 0; r < 4; ++r)
                    Y[(size_t)(tm * 128 + wr * 64 + mi * 16 + grp * 4 + r) * D_
                      + tn * 128 + wc * 64 + ni * 16 + colL] = f_to_bf16(acc[mi][ni][r] * sc);
    } else {
        int tok_base = tm * 128 + wr * 64;        // multiple of 64
        int bb = tok_base >> 11;
        int s_hi = tok_base & (S_ - 1);
        #pragma unroll
        for (int mi = 0; mi < 4; ++mi)
            #pragma unroll
            for (int ni = 0; ni < 4; ++ni) {
                int n  = tn * 128 + wc * 64 + ni * 16 + colL;
                int hh = n >> 6, dk = n & 63;
                u16* vp = Vt + ((size_t)(bb * H_ + hh) * DK_ + dk) * S_ + s_hi;
                #pragma unroll
                for (int r = 0; r < 4; ++r) {
                    int m = mi * 16 + grp * 4 + r;
                    int mp_ = ((m >> 5) & 1) * 32 + ((m >> 2) & 3) * 8 + ((m >> 4) & 1) * 4 + (m & 3);
                    vp[mp_] = f_to_bf16(acc[mi][ni][r]);
                }
            }
    }
}

// ---------------- Output GEMM: 64x128 tiles, grid 512 (2 blocks/CU) ----------------
__global__ __launch_bounds__(256, 2) void gemm_out(const u16* __restrict__ Xa,
                                                   const u16* __restrict__ Wot,
                                                   float* __restrict__ out) {
    __shared__ u16 ldsA[2 * 2048];   // [buf][64 rows][32 k]
    __shared__ u16 ldsB[2 * 4096];   // [buf][128 rows][32 k]
    int tm = blockIdx.x, tn = blockIdx.y;   // (64, 8)
    int t = threadIdx.x, l = t & 63;
    int w = t >> 6, wr = w >> 1, wc = w & 1;
    int colL = l & 15, grp = l >> 4;
    int sw4 = (grp ^ ((colL >> 1) & 3)) << 3;
    int f0 = t, f1 = t + 256;
    int row0 = f0 >> 2, kc0 = (((f0 & 3) ^ ((f0 >> 3) & 3)) << 3);
    int row1 = f1 >> 2, kc1 = (((f1 & 3) ^ ((f1 >> 3) & 3)) << 3);
    const u16* gA0 = Xa  + (size_t)(tm * 64 + row0) * D_ + kc0;    // 64 rows: chunk f0 only
    const u16* gB0 = Wot + (size_t)(tn * 128 + row0) * D_ + kc0;
    const u16* gB1 = Wot + (size_t)(tn * 128 + row1) * D_ + kc1;

    float4_ acc[2][4];
    #pragma unroll
    for (int mi = 0; mi < 2; ++mi)
        #pragma unroll
        for (int ni = 0; ni < 4; ++ni)
            acc[mi][ni] = (float4_){0.f, 0.f, 0.f, 0.f};

    gl_lds16(gA0, ldsA + f0 * 8);
    gl_lds16(gB0, ldsB + f0 * 8);
    gl_lds16(gB1, ldsB + f1 * 8);

    for (int k0 = 0; k0 < D_; k0 += 32) {
        int cur = (k0 >> 5) & 1;
        if (k0 + 32 < D_) {
            gl_lds16(gA0 + k0 + 32, ldsA + (cur ^ 1) * 2048 + f0 * 8);
            gl_lds16(gB0 + k0 + 32, ldsB + (cur ^ 1) * 4096 + f0 * 8);
            gl_lds16(gB1 + k0 + 32, ldsB + (cur ^ 1) * 4096 + f1 * 8);
            asm volatile("s_waitcnt vmcnt(3)" ::: "memory");   // tile t landed
        } else {
            asm volatile("s_waitcnt vmcnt(0)" ::: "memory");
        }
        __builtin_amdgcn_s_barrier();
        const u16* cA = ldsA + cur * 2048;
        const u16* cB = ldsB + cur * 4096;
        short8 a[2], b[4];
        #pragma unroll
        for (int mi = 0; mi < 2; ++mi)
            a[mi] = *(const short8*)&cA[(wr * 32 + mi * 16 + colL) * 32 + sw4];
        #pragma unroll
        for (int ni = 0; ni < 4; ++ni)
            b[ni] = *(const short8*)&cB[(wc * 64 + ni * 16 + colL) * 32 + sw4];
        #pragma unroll
        for (int mi = 0; mi < 2; ++mi)
            #pragma unroll
            for (int ni = 0; ni < 4; ++ni)
                acc[mi][ni] = __builtin_amdgcn_mfma_f32_16x16x32_bf16(a[mi], b[ni], acc[mi][ni], 0, 0, 0);
        __builtin_amdgcn_s_barrier();
    }

    #pragma unroll
    for (int mi = 0; mi < 2; ++mi)
        #pragma unroll
        for (int ni = 0; ni < 4; ++ni)
            #pragma unroll
            for (int r = 0; r < 4; ++r)
                out[(size_t)(tm * 64 + wr * 32 + mi * 16 + grp * 4 + r) * D_
                    + tn * 128 + wc * 64 + ni * 16 + colL] = acc[mi][ni][r];
}

// ---------------- flash attention: R9 phase-ordered body ----------------
// T4 counted-vmcnt double-buffer + T1 XCD swizzle. Wave owns 32 queries as two
// fragment sets; scores via mfma(K, Q); P in registers; softmax denominator on
// the matrix pipe. Phase-ordered (all-QK -> all-softmax -> all-PV).
__global__ __launch_bounds__(256, 2) void attn128(const u16* __restrict__ Qp,
                                                  const u16* __restrict__ Kp,
                                                  const u16* __restrict__ Vt,
                                                  const u64* __restrict__ mp,
                                                  u16* __restrict__ Xa) {
    __shared__ u16 ldsK[2 * 128 * 64];    // 2 bufs: [key 0..127][dim 64], chunk-swizzled
    __shared__ u16 ldsV[2 * 2 * 64 * 64]; // 2 bufs: two 64-key regions [dk 64][key 64]

    int bid0 = blockIdx.x;
    int bid = ((bid0 & 7) << 6) | (bid0 >> 3);   // XCD-contiguous (nwg=512, bijective)
    int qt = bid & 15, h = (bid >> 4) & 15, b = bid >> 8;
    int t = threadIdx.x, l = t & 63, w = t >> 6;
    int colL = l & 15, grp = l >> 4;

    const u16* qbA = Qp + (size_t)(b * S_ + qt * 128 + w * 32 + colL) * D_ + h * DK_;
    const u16* qbB = qbA + (size_t)16 * D_;
    short8 qfA0 = *(const short8*)(qbA + grp * 8);
    short8 qfA1 = *(const short8*)(qbA + 32 + grp * 8);
    short8 qfB0 = *(const short8*)(qbB + grp * 8);
    short8 qfB1 = *(const short8*)(qbB + 32 + grp * 8);

    const u16* gK[4];
    const u16* gV[4];
    int fofs[4];
    #pragma unroll
    for (int i = 0; i < 4; ++i) {
        int f = t + 256 * i;
        fofs[i] = f * 8;
        int krow = f >> 3, kch = (((f & 7) ^ (krow & 7)) << 3);
        gK[i] = Kp + (size_t)(b * S_ + krow) * D_ + h * DK_ + kch;
        int hreg = f >> 9, fp = f & 511;
        int vrow = fp >> 3, vch = (((fp & 7) ^ (vrow & 7)) << 3);
        gV[i] = Vt + ((size_t)(b * H_ + h) * DK_ + vrow) * S_ + hreg * 64 + vch;
    }

    int sw8 = (grp ^ (colL & 7)) << 3;

    short8 onesb;
    #pragma unroll
    for (int j = 0; j < 8; ++j) onesb[j] = (short)0x3F80;

    float4_ laccA = (float4_){0.f, 0.f, 0.f, 0.f};
    float4_ laccB = (float4_){0.f, 0.f, 0.f, 0.f};
    float4_ oA[4], oB[4];
    #pragma unroll
    for (int nt = 0; nt < 4; ++nt) {
        oA[nt] = (float4_){0.f, 0.f, 0.f, 0.f};
        oB[nt] = (float4_){0.f, 0.f, 0.f, 0.f};
    }

    const u64* mrA = mp + (size_t)(b * S_ + qt * 128 + w * 32 + colL) * SW_;
    const u64* mrB = mrA + (size_t)16 * SW_;

    #pragma unroll
    for (int i = 0; i < 4; ++i) {
        gl_lds16(gK[i], ldsK + fofs[i]);
        gl_lds16(gV[i], ldsV + fofs[i]);
    }

    for (int kt = 0; kt < S_; kt += 128) {
        int cur = (kt >> 7) & 1;

        u64 mwA0 = mrA[(kt >> 6)];
        u64 mwA1 = mrA[(kt >> 6) + 1];
        u64 mwB0 = mrB[(kt >> 6)];
        u64 mwB1 = mrB[(kt >> 6) + 1];

        if (kt + 128 < S_) {
            int nb = (cur ^ 1) * 8192;
            #pragma unroll
            for (int i = 0; i < 4; ++i) {
                gl_lds16(gK[i] + (size_t)(kt + 128) * D_, ldsK + nb + fofs[i]);
                gl_lds16(gV[i] + (kt + 128),              ldsV + nb + fofs[i]);
            }
            asm volatile("s_waitcnt vmcnt(12)" ::: "memory");
        } else {
            asm volatile("s_waitcnt vmcnt(4)" ::: "memory");
        }
        __builtin_amdgcn_s_barrier();

        const u16* K_ = ldsK + cur * 8192;
        const u16* V_ = ldsV + cur * 8192;

        float4_ sA[8], sB[8];
        __builtin_amdgcn_s_setprio(1);
        #pragma unroll
        for (int nt = 0; nt < 8; ++nt) {
            int ro = (nt * 16 + colL) * 64;
            short8 kf0 = *(const short8*)&K_[ro + sw8];
            short8 kf1 = *(const short8*)&K_[ro + (sw8 ^ 32)];
            sA[nt] = (float4_){0.f, 0.f, 0.f, 0.f};
            sA[nt] = __builtin_amdgcn_mfma_f32_16x16x32_bf16(kf0, qfA0, sA[nt], 0, 0, 0);
            sA[nt] = __builtin_amdgcn_mfma_f32_16x16x32_bf16(kf1, qfA1, sA[nt], 0, 0, 0);
            sB[nt] = (float4_){0.f, 0.f, 0.f, 0.f};
            sB[nt] = __builtin_amdgcn_mfma_f32_16x16x32_bf16(kf0, qfB0, sB[nt], 0, 0, 0);
            sB[nt] = __builtin_amdgcn_mfma_f32_16x16x32_bf16(kf1, qfB1, sB[nt], 0, 0, 0);
        }
        __builtin_amdgcn_s_setprio(0);

        u64 mshA0 = mwA0 >> (grp * 4), mshA1 = mwA1 >> (grp * 4);
        u64 mshB0 = mwB0 >> (grp * 4), mshB1 = mwB1 >> (grp * 4);
        #pragma unroll
        for (int nt = 0; nt < 8; ++nt) {
            u32 bitsA = ((u32)((nt < 4 ? mshA0 : mshA1) >> ((nt & 3) * 16))) & 15u;
            u32 bitsB = ((u32)((nt < 4 ? mshB0 : mshB1) >> ((nt & 3) * 16))) & 15u;
            #pragma unroll
            for (int r = 0; r < 4; ++r) {
                float pA = fast_exp2(sA[nt][r]);
                float pB = fast_exp2(sB[nt][r]);
                u32 keepA = 0u - ((bitsA >> r) & 1u);
                u32 keepB = 0u - ((bitsB >> r) & 1u);
                union { float f; u32 i; } ua, ub;
                ua.f = pA; ua.i &= keepA; sA[nt][r] = ua.f;
                ub.f = pB; ub.i &= keepB; sB[nt][r] = ub.f;
            }
        }

        short8 pfA[4], pfB[4];
        #pragma unroll
        for (int j = 0; j < 4; ++j) {
            uint4_ Ax = { cvtpk(sA[2 * j][0], sA[2 * j][1]), cvtpk(sA[2 * j][2], sA[2 * j][3]),
                          cvtpk(sA[2 * j + 1][0], sA[2 * j + 1][1]), cvtpk(sA[2 * j + 1][2], sA[2 * j + 1][3]) };
            pfA[j] = __builtin_bit_cast(short8, Ax);
            uint4_ Bx = { cvtpk(sB[2 * j][0], sB[2 * j][1]), cvtpk(sB[2 * j][2], sB[2 * j][3]),
                          cvtpk(sB[2 * j + 1][0], sB[2 * j + 1][1]), cvtpk(sB[2 * j + 1][2], sB[2 * j + 1][3]) };
            pfB[j] = __builtin_bit_cast(short8, Bx);
        }

        __builtin_amdgcn_s_setprio(1);
        #pragma unroll
        for (int nt = 0; nt < 4; ++nt) {
            int ro = (nt * 16 + colL) * 64;
            short8 vf0 = *(const short8*)&V_[ro + sw8];
            short8 vf1 = *(const short8*)&V_[ro + (sw8 ^ 32)];
            short8 vf2 = *(const short8*)&V_[4096 + ro + sw8];
            short8 vf3 = *(const short8*)&V_[4096 + ro + (sw8 ^ 32)];
            oA[nt] = __builtin_amdgcn_mfma_f32_16x16x32_bf16(pfA[0], vf0, oA[nt], 0, 0, 0);
            oA[nt] = __builtin_amdgcn_mfma_f32_16x16x32_bf16(pfA[1], vf1, oA[nt], 0, 0, 0);
            oA[nt] = __builtin_amdgcn_mfma_f32_16x16x32_bf16(pfA[2], vf2, oA[nt], 0, 0, 0);
            oA[nt] = __builtin_amdgcn_mfma_f32_16x16x32_bf16(pfA[3], vf3, oA[nt], 0, 0, 0);
            oB[nt] = __builtin_amdgcn_mfma_f32_16x16x32_bf16(pfB[0], vf0, oB[nt], 0, 0, 0);
            oB[nt] = __builtin_amdgcn_mfma_f32_16x16x32_bf16(pfB[1], vf1, oB[nt], 0, 0, 0);
            oB[nt] = __builtin_amdgcn_mfma_f32_16x16x32_bf16(pfB[2], vf2, oB[nt], 0, 0, 0);
            oB[nt] = __builtin_amdgcn_mfma_f32_16x16x32_bf16(pfB[3], vf3, oB[nt], 0, 0, 0);
        }
        laccA = __builtin_amdgcn_mfma_f32_16x16x32_bf16(pfA[0], onesb, laccA, 0, 0, 0);
        laccA = __builtin_amdgcn_mfma_f32_16x16x32_bf16(pfA[1], onesb, laccA, 0, 0, 0);
        laccA = __builtin_amdgcn_mfma_f32_16x16x32_bf16(pfA[2], onesb, laccA, 0, 0, 0);
        laccA = __builtin_amdgcn_mfma_f32_16x16x32_bf16(pfA[3], onesb, laccA, 0, 0, 0);
        laccB = __builtin_amdgcn_mfma_f32_16x16x32_bf16(pfB[0], onesb, laccB, 0, 0, 0);
        laccB = __builtin_amdgcn_mfma_f32_16x16x32_bf16(pfB[1], onesb, laccB, 0, 0, 0);
        laccB = __builtin_amdgcn_mfma_f32_16x16x32_bf16(pfB[2], onesb, laccB, 0, 0, 0);
        laccB = __builtin_amdgcn_mfma_f32_16x16x32_bf16(pfB[3], onesb, laccB, 0, 0, 0);
        __builtin_amdgcn_s_setprio(0);

        __builtin_amdgcn_s_barrier();
    }

    float invA[4], invB[4];
    #pragma unroll
    for (int r = 0; r < 4; ++r) {
        invA[r] = 1.f / laccA[r];
        invB[r] = 1.f / laccB[r];
    }

    u16* xoA = Xa + (size_t)(b * S_ + qt * 128 + w * 32 + grp * 4) * D_ + h * DK_;
    u16* xoB = xoA + (size_t)16 * D_;
    #pragma unroll
    for (int r = 0; r < 4; ++r)
        #pragma unroll
        for (int nt = 0; nt < 4; ++nt) {
            xoA[(size_t)r * D_ + nt * 16 + colL] = f_to_bf16(oA[nt][r] * invA[r]);
            xoB[(size_t)r * D_ + nt * 16 + colL] = f_to_bf16(oB[nt][r] * invB[r]);
        }
}

extern "C" void kernel_launch(void* const* d_in, const int* in_sizes, int n_in,
                              void* d_out, int out_size, void* d_ws, size_t ws_size,
                              hipStream_t stream) {
    const float* q    = (const float*)d_in[0];
    const float* k    = (const float*)d_in[1];
    const float* v    = (const float*)d_in[2];
    const int*   mask = (const int*)d_in[3];
    const float* Wq   = (const float*)d_in[4];
    const float* Wk   = (const float*)d_in[5];
    const float* Wv   = (const float*)d_in[6];
    const float* Wo   = (const float*)d_in[7];
    float* out = (float*)d_out;

    const int NQ = B_ * S_ * D_;   // 4,194,304
    const int NW = D_ * D_;        // 1,048,576

    u16* qb  = (u16*)d_ws;
    u16* kb  = qb  + NQ;
    u16* vb  = kb  + NQ;
    u16* Wqt = vb  + NQ;
    u16* Wkt = Wqt + NW;
    u16* Wvt = Wkt + NW;
    u16* Wot = Wvt + NW;
    u16* Qp  = Wot + NW;
    u16* Kp  = Qp  + NQ;
    u16* Vt  = Kp  + NQ;   // [B][H][DK][tau(S)]
    u16* Xa  = Vt  + NQ;
    u64* mpk = (u64*)(Xa + NQ);    // 1 MB packed mask

    dim3 cblk(256);
    prep<<<10240, cblk, 0, stream>>>(q, k, v, Wq, Wk, Wv, Wo,
                                     qb, kb, vb, Wqt, Wkt, Wvt, Wot);

    const int M = B_ * S_;  // 4096
    gemm_qkv<<<dim3(M / 128, D_ / 128, 19), cblk, 0, stream>>>(qb, kb, vb, Wqt, Wkt, Wvt,
                                                               Qp, Kp, Vt, mask, mpk);

    attn128<<<B_ * H_ * (S_ / 128), cblk, 0, stream>>>(Qp, Kp, Vt, mpk, Xa);

    gemm_out<<<dim3(M / 64, D_ / 128), cblk, 0, stream>>>(Xa, Wot, out);
}

// Round 13
// 237.678 us; speedup vs baseline: 1.0582x; 1.0582x over previous
//
#include <hip/hip_runtime.h>
#include <hip/hip_bf16.h>
#include <math.h>

#define B_ 2
#define S_ 2048
#define D_ 1024
#define H_ 16
#define DK_ 64
#define SW_ (S_ / 64)   // 32 packed mask words per row

typedef unsigned short u16;
typedef unsigned int u32;
typedef unsigned long long u64;
typedef __attribute__((ext_vector_type(8))) short short8;
typedef __attribute__((ext_vector_type(4))) float float4_;
typedef __attribute__((ext_vector_type(4))) unsigned int uint4_;

static __device__ inline u16 f_to_bf16(float f) {
    union { float f; u32 i; } x; x.f = f;
    u32 r = x.i + 0x7fff + ((x.i >> 16) & 1);  // RNE
    return (u16)(r >> 16);
}

// two f32 -> packed u32 of two bf16 (RNE), low half = first arg
static __device__ __forceinline__ u32 packrne(float a, float b) {
    union { float f; u32 i; } xa, xb; xa.f = a; xb.f = b;
    u32 lo = (xa.i + 0x7fff + ((xa.i >> 16) & 1)) >> 16;
    u32 hi = (xb.i + 0x7fff + ((xb.i >> 16) & 1)) & 0xffff0000u;
    return lo | hi;
}

// hw packed f32x2 -> bf16x2 (low = a). Single VOP3 vs ~5 int ops.
static __device__ __forceinline__ u32 cvtpk(float a, float b) {
    u32 r;
    asm("v_cvt_pk_bf16_f32 %0, %1, %2" : "=v"(r) : "v"(a), "v"(b));
    return r;
}

static __device__ __forceinline__ float fast_exp2(float x) {
#if __has_builtin(__builtin_amdgcn_exp2f)
    return __builtin_amdgcn_exp2f(x);   // bare v_exp_f32
#else
    return exp2f(x);
#endif
}

// async global->LDS, 16B per lane (wave-uniform base + lane*16).
static __device__ inline void gl_lds16(const u16* g, u16* l) {
    __builtin_amdgcn_global_load_lds((const __attribute__((address_space(1))) void*)g,
                                     (__attribute__((address_space(3))) void*)l, 16, 0, 0);
}

// ---------------- fused prep: cvt3 (vectorized) | wtrans4 | mpack ----------------
// Wide (14336 blocks): all three sections are memory-bound and latency-rich, so
// they overlap each other across the grid. Moving any section into a saturated
// MFMA dispatch serializes it instead (measured: R8 +25 us, R12 +11 us).
__global__ __launch_bounds__(256) void prep(const float* __restrict__ q,
                                            const float* __restrict__ k,
                                            const float* __restrict__ v,
                                            const int* __restrict__ mask,
                                            const float* __restrict__ W0,
                                            const float* __restrict__ W1,
                                            const float* __restrict__ W2,
                                            const float* __restrict__ W3,
                                            u16* __restrict__ qb, u16* __restrict__ kb,
                                            u16* __restrict__ vb,
                                            u16* __restrict__ T0, u16* __restrict__ T1,
                                            u16* __restrict__ T2, u16* __restrict__ T3,
                                            u64* __restrict__ mpk) {
    __shared__ float tile[32][33];
    int gx = blockIdx.x, tid = threadIdx.x;
    if (gx < 6144) {                       // fp32 -> bf16, q/k/v (16B vector store)
        int z = gx >> 11;
        int bx = gx & 2047;
        const float* s = (z == 0) ? q : ((z == 1) ? k : v);
        u16* d = (z == 0) ? qb : ((z == 1) ? kb : vb);
        int i = (bx * 256 + tid) * 8;
        float4_ a0 = *(const float4_*)(s + i);
        float4_ a1 = *(const float4_*)(s + i + 4);
        uint4_ wv_ = { packrne(a0[0], a0[1]), packrne(a0[2], a0[3]),
                       packrne(a1[0], a1[1]), packrne(a1[2], a1[3]) };
        *(uint4_*)(d + i) = wv_;
    } else if (gx < 10240) {               // W^T x4
        int g2 = gx - 6144;
        int z = g2 >> 10;
        int rem = g2 & 1023;
        const float* W = (z == 0) ? W0 : ((z == 1) ? W1 : ((z == 2) ? W2 : W3));
        u16* Wt = (z == 0) ? T0 : ((z == 1) ? T1 : ((z == 2) ? T2 : T3));
        int k0 = (rem >> 5) * 32, n0 = (rem & 31) * 32;
        int tx = tid & 31, ty = tid >> 5;
        #pragma unroll
        for (int i2 = 0; i2 < 4; ++i2) {
            int row = ty + i2 * 8;
            tile[row][tx] = W[(size_t)(k0 + row) * D_ + n0 + tx];
        }
        __syncthreads();
        #pragma unroll
        for (int i2 = 0; i2 < 4; ++i2) {
            int row = ty + i2 * 8;
            Wt[(size_t)(n0 + row) * D_ + k0 + tx] = f_to_bf16(tile[tx][row]);
        }
    } else {                               // mask bit-pack (wide: 4096 blocks)
        int g3 = gx - 10240;
        int wv = (g3 * 256 + tid) >> 6;
        int lane = tid & 63;
        #pragma unroll
        for (int i2 = 0; i2 < 8; ++i2) {
            int wd = wv * 8 + i2;
            u64 bits = __ballot(mask[(size_t)wd * 64 + lane] != 0);
            if (lane == 0) mpk[wd] = bits;
        }
    }
}

// ---------------- 128x128x32-step GEMM body, T4 counted-vmcnt dbuf ----------------
static __device__ __forceinline__ void gemm128_body(u16* lds,
                                                    const u16* __restrict__ A,
                                                    const u16* __restrict__ Bt,
                                                    int K, float4_ (&acc)[4][4]) {
    u16* ldsA = lds;            // 2 bufs x 128*32
    u16* ldsB = lds + 8192;     // 2 bufs x 128*32
    int tm = blockIdx.x, tn = blockIdx.y;
    int t = threadIdx.x, l = t & 63;
    int w = t >> 6, wr = w >> 1, wc = w & 1;
    int colL = l & 15, grp = l >> 4;
    int sw4 = (grp ^ ((colL >> 1) & 3)) << 3;
    int f0 = t, f1 = t + 256;
    int row0 = f0 >> 2, kc0 = (((f0 & 3) ^ ((f0 >> 3) & 3)) << 3);
    int row1 = f1 >> 2, kc1 = (((f1 & 3) ^ ((f1 >> 3) & 3)) << 3);
    const u16* gA0 = A  + (size_t)(tm * 128 + row0) * K + kc0;
    const u16* gA1 = A  + (size_t)(tm * 128 + row1) * K + kc1;
    const u16* gB0 = Bt + (size_t)(tn * 128 + row0) * K + kc0;
    const u16* gB1 = Bt + (size_t)(tn * 128 + row1) * K + kc1;

    #pragma unroll
    for (int mi = 0; mi < 4; ++mi)
        #pragma unroll
        for (int ni = 0; ni < 4; ++ni)
            acc[mi][ni] = (float4_){0.f, 0.f, 0.f, 0.f};

    // prologue: stage k-tile 0 into buf 0
    gl_lds16(gA0, ldsA + f0 * 8);
    gl_lds16(gA1, ldsA + f1 * 8);
    gl_lds16(gB0, ldsB + f0 * 8);
    gl_lds16(gB1, ldsB + f1 * 8);

    for (int k0 = 0; k0 < K; k0 += 32) {
        int cur = (k0 >> 5) & 1;
        if (k0 + 32 < K) {
            int nb = (cur ^ 1) * 4096;
            gl_lds16(gA0 + k0 + 32, ldsA + nb + f0 * 8);
            gl_lds16(gA1 + k0 + 32, ldsA + nb + f1 * 8);
            gl_lds16(gB0 + k0 + 32, ldsB + nb + f0 * 8);
            gl_lds16(gB1 + k0 + 32, ldsB + nb + f1 * 8);
            asm volatile("s_waitcnt vmcnt(4)" ::: "memory");   // tile k0 landed
        } else {
            asm volatile("s_waitcnt vmcnt(0)" ::: "memory");
        }
        __builtin_amdgcn_s_barrier();      // all waves: tile k0 in LDS
        const u16* cA = ldsA + cur * 4096;
        const u16* cB = ldsB + cur * 4096;
        short8 a[4], b[4];
        #pragma unroll
        for (int mi = 0; mi < 4; ++mi)
            a[mi] = *(const short8*)&cA[(wr * 64 + mi * 16 + colL) * 32 + sw4];
        #pragma unroll
        for (int ni = 0; ni < 4; ++ni)
            b[ni] = *(const short8*)&cB[(wc * 64 + ni * 16 + colL) * 32 + sw4];
        #pragma unroll
        for (int mi = 0; mi < 4; ++mi)
            #pragma unroll
            for (int ni = 0; ni < 4; ++ni)
                acc[mi][ni] = __builtin_amdgcn_mfma_f32_16x16x32_bf16(a[mi], b[ni], acc[mi][ni], 0, 0, 0);
        __builtin_amdgcn_s_barrier();      // reads of buf[cur] done (next iter overwrites it)
    }
}

// QKV fused: z = 0/1/2 -> Q/K/V.
// z==0: Q scaled by 0.125*log2(e). z==2: V scattered to Vt[b][h][dk][tau(s)].
__global__ __launch_bounds__(256, 3) void gemm_qkv(const u16* __restrict__ qb,
                                                   const u16* __restrict__ kb,
                                                   const u16* __restrict__ vb,
                                                   const u16* __restrict__ Wqt,
                                                   const u16* __restrict__ Wkt,
                                                   const u16* __restrict__ Wvt,
                                                   u16* __restrict__ Qp,
                                                   u16* __restrict__ Kp,
                                                   u16* __restrict__ Vt) {
    __shared__ u16 lds[16384];
    int z = blockIdx.z;
    const u16* A  = (z == 0) ? qb  : ((z == 1) ? kb  : vb);
    const u16* Bt = (z == 0) ? Wqt : ((z == 1) ? Wkt : Wvt);
    float4_ acc[4][4];
    gemm128_body(lds, A, Bt, D_, acc);

    int tm = blockIdx.x, tn = blockIdx.y;
    int t = threadIdx.x, l = t & 63;
    int w = t >> 6, wr = w >> 1, wc = w & 1;
    int colL = l & 15, grp = l >> 4;

    if (z < 2) {
        u16* Y = (z == 0) ? Qp : Kp;
        float sc = (z == 0) ? (0.125f * 1.44269504f) : 1.0f;
        #pragma unroll
        for (int mi = 0; mi < 4; ++mi)
            #pragma unroll
            for (int ni = 0; ni < 4; ++ni)
                #pragma unroll
                for (int r = 0; r < 4; ++r)
                    Y[(size_t)(tm * 128 + wr * 64 + mi * 16 + grp * 4 + r) * D_
                      + tn * 128 + wc * 64 + ni * 16 + colL] = f_to_bf16(acc[mi][ni][r] * sc);
    } else {
        int tok_base = tm * 128 + wr * 64;        // multiple of 64
        int bb = tok_base >> 11;
        int s_hi = tok_base & (S_ - 1);
        #pragma unroll
        for (int mi = 0; mi < 4; ++mi)
            #pragma unroll
            for (int ni = 0; ni < 4; ++ni) {
                int n  = tn * 128 + wc * 64 + ni * 16 + colL;
                int hh = n >> 6, dk = n & 63;
                u16* vp = Vt + ((size_t)(bb * H_ + hh) * DK_ + dk) * S_ + s_hi;
                #pragma unroll
                for (int r = 0; r < 4; ++r) {
                    int m = mi * 16 + grp * 4 + r;
                    int mp_ = ((m >> 5) & 1) * 32 + ((m >> 2) & 3) * 8 + ((m >> 4) & 1) * 4 + (m & 3);
                    vp[mp_] = f_to_bf16(acc[mi][ni][r]);
                }
            }
    }
}

// ---------------- Output GEMM: 64x128 tiles, grid 512 (2 blocks/CU) ----------------
__global__ __launch_bounds__(256, 2) void gemm_out(const u16* __restrict__ Xa,
                                                   const u16* __restrict__ Wot,
                                                   float* __restrict__ out) {
    __shared__ u16 ldsA[2 * 2048];   // [buf][64 rows][32 k]
    __shared__ u16 ldsB[2 * 4096];   // [buf][128 rows][32 k]
    int tm = blockIdx.x, tn = blockIdx.y;   // (64, 8)
    int t = threadIdx.x, l = t & 63;
    int w = t >> 6, wr = w >> 1, wc = w & 1;
    int colL = l & 15, grp = l >> 4;
    int sw4 = (grp ^ ((colL >> 1) & 3)) << 3;
    int f0 = t, f1 = t + 256;
    int row0 = f0 >> 2, kc0 = (((f0 & 3) ^ ((f0 >> 3) & 3)) << 3);
    int row1 = f1 >> 2, kc1 = (((f1 & 3) ^ ((f1 >> 3) & 3)) << 3);
    const u16* gA0 = Xa  + (size_t)(tm * 64 + row0) * D_ + kc0;    // 64 rows: chunk f0 only
    const u16* gB0 = Wot + (size_t)(tn * 128 + row0) * D_ + kc0;
    const u16* gB1 = Wot + (size_t)(tn * 128 + row1) * D_ + kc1;

    float4_ acc[2][4];
    #pragma unroll
    for (int mi = 0; mi < 2; ++mi)
        #pragma unroll
        for (int ni = 0; ni < 4; ++ni)
            acc[mi][ni] = (float4_){0.f, 0.f, 0.f, 0.f};

    gl_lds16(gA0, ldsA + f0 * 8);
    gl_lds16(gB0, ldsB + f0 * 8);
    gl_lds16(gB1, ldsB + f1 * 8);

    for (int k0 = 0; k0 < D_; k0 += 32) {
        int cur = (k0 >> 5) & 1;
        if (k0 + 32 < D_) {
            gl_lds16(gA0 + k0 + 32, ldsA + (cur ^ 1) * 2048 + f0 * 8);
            gl_lds16(gB0 + k0 + 32, ldsB + (cur ^ 1) * 4096 + f0 * 8);
            gl_lds16(gB1 + k0 + 32, ldsB + (cur ^ 1) * 4096 + f1 * 8);
            asm volatile("s_waitcnt vmcnt(3)" ::: "memory");   // tile t landed
        } else {
            asm volatile("s_waitcnt vmcnt(0)" ::: "memory");
        }
        __builtin_amdgcn_s_barrier();
        const u16* cA = ldsA + cur * 2048;
        const u16* cB = ldsB + cur * 4096;
        short8 a[2], b[4];
        #pragma unroll
        for (int mi = 0; mi < 2; ++mi)
            a[mi] = *(const short8*)&cA[(wr * 32 + mi * 16 + colL) * 32 + sw4];
        #pragma unroll
        for (int ni = 0; ni < 4; ++ni)
            b[ni] = *(const short8*)&cB[(wc * 64 + ni * 16 + colL) * 32 + sw4];
        #pragma unroll
        for (int mi = 0; mi < 2; ++mi)
            #pragma unroll
            for (int ni = 0; ni < 4; ++ni)
                acc[mi][ni] = __builtin_amdgcn_mfma_f32_16x16x32_bf16(a[mi], b[ni], acc[mi][ni], 0, 0, 0);
        __builtin_amdgcn_s_barrier();
    }

    #pragma unroll
    for (int mi = 0; mi < 2; ++mi)
        #pragma unroll
        for (int ni = 0; ni < 4; ++ni)
            #pragma unroll
            for (int r = 0; r < 4; ++r)
                out[(size_t)(tm * 64 + wr * 32 + mi * 16 + grp * 4 + r) * D_
                    + tn * 128 + wc * 64 + ni * 16 + colL] = acc[mi][ni][r];
}

// ---------------- flash attention: R9 phase-ordered body ----------------
// T4 counted-vmcnt double-buffer + T1 XCD swizzle. Wave owns 32 queries as two
// fragment sets; scores via mfma(K, Q); P in registers; softmax denominator on
// the matrix pipe. Phase-ordered (all-QK -> all-softmax -> all-PV): the wide
// independent window lets the compiler software-pipeline; j-grouping measured
// worse — do not re-shorten the scheduling window.
__global__ __launch_bounds__(256, 2) void attn128(const u16* __restrict__ Qp,
                                                  const u16* __restrict__ Kp,
                                                  const u16* __restrict__ Vt,
                                                  const u64* __restrict__ mp,
                                                  u16* __restrict__ Xa) {
    __shared__ u16 ldsK[2 * 128 * 64];    // 2 bufs: [key 0..127][dim 64], chunk-swizzled
    __shared__ u16 ldsV[2 * 2 * 64 * 64]; // 2 bufs: two 64-key regions [dk 64][key 64]

    int bid0 = blockIdx.x;
    int bid = ((bid0 & 7) << 6) | (bid0 >> 3);   // XCD-contiguous (nwg=512, bijective)
    int qt = bid & 15, h = (bid >> 4) & 15, b = bid >> 8;
    int t = threadIdx.x, l = t & 63, w = t >> 6;
    int colL = l & 15, grp = l >> 4;

    const u16* qbA = Qp + (size_t)(b * S_ + qt * 128 + w * 32 + colL) * D_ + h * DK_;
    const u16* qbB = qbA + (size_t)16 * D_;
    short8 qfA0 = *(const short8*)(qbA + grp * 8);
    short8 qfA1 = *(const short8*)(qbA + 32 + grp * 8);
    short8 qfB0 = *(const short8*)(qbB + grp * 8);
    short8 qfB1 = *(const short8*)(qbB + 32 + grp * 8);

    const u16* gK[4];
    const u16* gV[4];
    int fofs[4];
    #pragma unroll
    for (int i = 0; i < 4; ++i) {
        int f = t + 256 * i;
        fofs[i] = f * 8;
        int krow = f >> 3, kch = (((f & 7) ^ (krow & 7)) << 3);
        gK[i] = Kp + (size_t)(b * S_ + krow) * D_ + h * DK_ + kch;
        int hreg = f >> 9, fp = f & 511;
        int vrow = fp >> 3, vch = (((fp & 7) ^ (vrow & 7)) << 3);
        gV[i] = Vt + ((size_t)(b * H_ + h) * DK_ + vrow) * S_ + hreg * 64 + vch;
    }

    int sw8 = (grp ^ (colL & 7)) << 3;

    short8 onesb;
    #pragma unroll
    for (int j = 0; j < 8; ++j) onesb[j] = (short)0x3F80;

    float4_ laccA = (float4_){0.f, 0.f, 0.f, 0.f};
    float4_ laccB = (float4_){0.f, 0.f, 0.f, 0.f};
    float4_ oA[4], oB[4];
    #pragma unroll
    for (int nt = 0; nt < 4; ++nt) {
        oA[nt] = (float4_){0.f, 0.f, 0.f, 0.f};
        oB[nt] = (float4_){0.f, 0.f, 0.f, 0.f};
    }

    const u64* mrA = mp + (size_t)(b * S_ + qt * 128 + w * 32 + colL) * SW_;
    const u64* mrB = mrA + (size_t)16 * SW_;

    #pragma unroll
    for (int i = 0; i < 4; ++i) {
        gl_lds16(gK[i], ldsK + fofs[i]);
        gl_lds16(gV[i], ldsV + fofs[i]);
    }

    for (int kt = 0; kt < S_; kt += 128) {
        int cur = (kt >> 7) & 1;

        u64 mwA0 = mrA[(kt >> 6)];
        u64 mwA1 = mrA[(kt >> 6) + 1];
        u64 mwB0 = mrB[(kt >> 6)];
        u64 mwB1 = mrB[(kt >> 6) + 1];

        if (kt + 128 < S_) {
            int nb = (cur ^ 1) * 8192;
            #pragma unroll
            for (int i = 0; i < 4; ++i) {
                gl_lds16(gK[i] + (size_t)(kt + 128) * D_, ldsK + nb + fofs[i]);
                gl_lds16(gV[i] + (kt + 128),              ldsV + nb + fofs[i]);
            }
            asm volatile("s_waitcnt vmcnt(12)" ::: "memory");
        } else {
            asm volatile("s_waitcnt vmcnt(4)" ::: "memory");
        }
        __builtin_amdgcn_s_barrier();

        const u16* K_ = ldsK + cur * 8192;
        const u16* V_ = ldsV + cur * 8192;

        float4_ sA[8], sB[8];
        __builtin_amdgcn_s_setprio(1);
        #pragma unroll
        for (int nt = 0; nt < 8; ++nt) {
            int ro = (nt * 16 + colL) * 64;
            short8 kf0 = *(const short8*)&K_[ro + sw8];
            short8 kf1 = *(const short8*)&K_[ro + (sw8 ^ 32)];
            sA[nt] = (float4_){0.f, 0.f, 0.f, 0.f};
            sA[nt] = __builtin_amdgcn_mfma_f32_16x16x32_bf16(kf0, qfA0, sA[nt], 0, 0, 0);
            sA[nt] = __builtin_amdgcn_mfma_f32_16x16x32_bf16(kf1, qfA1, sA[nt], 0, 0, 0);
            sB[nt] = (float4_){0.f, 0.f, 0.f, 0.f};
            sB[nt] = __builtin_amdgcn_mfma_f32_16x16x32_bf16(kf0, qfB0, sB[nt], 0, 0, 0);
            sB[nt] = __builtin_amdgcn_mfma_f32_16x16x32_bf16(kf1, qfB1, sB[nt], 0, 0, 0);
        }
        __builtin_amdgcn_s_setprio(0);

        u64 mshA0 = mwA0 >> (grp * 4), mshA1 = mwA1 >> (grp * 4);
        u64 mshB0 = mwB0 >> (grp * 4), mshB1 = mwB1 >> (grp * 4);
        #pragma unroll
        for (int nt = 0; nt < 8; ++nt) {
            u32 bitsA = ((u32)((nt < 4 ? mshA0 : mshA1) >> ((nt & 3) * 16))) & 15u;
            u32 bitsB = ((u32)((nt < 4 ? mshB0 : mshB1) >> ((nt & 3) * 16))) & 15u;
            #pragma unroll
            for (int r = 0; r < 4; ++r) {
                float pA = fast_exp2(sA[nt][r]);
                float pB = fast_exp2(sB[nt][r]);
                u32 keepA = 0u - ((bitsA >> r) & 1u);
                u32 keepB = 0u - ((bitsB >> r) & 1u);
                union { float f; u32 i; } ua, ub;
                ua.f = pA; ua.i &= keepA; sA[nt][r] = ua.f;
                ub.f = pB; ub.i &= keepB; sB[nt][r] = ub.f;
            }
        }

        short8 pfA[4], pfB[4];
        #pragma unroll
        for (int j = 0; j < 4; ++j) {
            uint4_ Ax = { cvtpk(sA[2 * j][0], sA[2 * j][1]), cvtpk(sA[2 * j][2], sA[2 * j][3]),
                          cvtpk(sA[2 * j + 1][0], sA[2 * j + 1][1]), cvtpk(sA[2 * j + 1][2], sA[2 * j + 1][3]) };
            pfA[j] = __builtin_bit_cast(short8, Ax);
            uint4_ Bx = { cvtpk(sB[2 * j][0], sB[2 * j][1]), cvtpk(sB[2 * j][2], sB[2 * j][3]),
                          cvtpk(sB[2 * j + 1][0], sB[2 * j + 1][1]), cvtpk(sB[2 * j + 1][2], sB[2 * j + 1][3]) };
            pfB[j] = __builtin_bit_cast(short8, Bx);
        }

        __builtin_amdgcn_s_setprio(1);
        #pragma unroll
        for (int nt = 0; nt < 4; ++nt) {
            int ro = (nt * 16 + colL) * 64;
            short8 vf0 = *(const short8*)&V_[ro + sw8];
            short8 vf1 = *(const short8*)&V_[ro + (sw8 ^ 32)];
            short8 vf2 = *(const short8*)&V_[4096 + ro + sw8];
            short8 vf3 = *(const short8*)&V_[4096 + ro + (sw8 ^ 32)];
            oA[nt] = __builtin_amdgcn_mfma_f32_16x16x32_bf16(pfA[0], vf0, oA[nt], 0, 0, 0);
            oA[nt] = __builtin_amdgcn_mfma_f32_16x16x32_bf16(pfA[1], vf1, oA[nt], 0, 0, 0);
            oA[nt] = __builtin_amdgcn_mfma_f32_16x16x32_bf16(pfA[2], vf2, oA[nt], 0, 0, 0);
            oA[nt] = __builtin_amdgcn_mfma_f32_16x16x32_bf16(pfA[3], vf3, oA[nt], 0, 0, 0);
            oB[nt] = __builtin_amdgcn_mfma_f32_16x16x32_bf16(pfB[0], vf0, oB[nt], 0, 0, 0);
            oB[nt] = __builtin_amdgcn_mfma_f32_16x16x32_bf16(pfB[1], vf1, oB[nt], 0, 0, 0);
            oB[nt] = __builtin_amdgcn_mfma_f32_16x16x32_bf16(pfB[2], vf2, oB[nt], 0, 0, 0);
            oB[nt] = __builtin_amdgcn_mfma_f32_16x16x32_bf16(pfB[3], vf3, oB[nt], 0, 0, 0);
        }
        laccA = __builtin_amdgcn_mfma_f32_16x16x32_bf16(pfA[0], onesb, laccA, 0, 0, 0);
        laccA = __builtin_amdgcn_mfma_f32_16x16x32_bf16(pfA[1], onesb, laccA, 0, 0, 0);
        laccA = __builtin_amdgcn_mfma_f32_16x16x32_bf16(pfA[2], onesb, laccA, 0, 0, 0);
        laccA = __builtin_amdgcn_mfma_f32_16x16x32_bf16(pfA[3], onesb, laccA, 0, 0, 0);
        laccB = __builtin_amdgcn_mfma_f32_16x16x32_bf16(pfB[0], onesb, laccB, 0, 0, 0);
        laccB = __builtin_amdgcn_mfma_f32_16x16x32_bf16(pfB[1], onesb, laccB, 0, 0, 0);
        laccB = __builtin_amdgcn_mfma_f32_16x16x32_bf16(pfB[2], onesb, laccB, 0, 0, 0);
        laccB = __builtin_amdgcn_mfma_f32_16x16x32_bf16(pfB[3], onesb, laccB, 0, 0, 0);
        __builtin_amdgcn_s_setprio(0);

        __builtin_amdgcn_s_barrier();
    }

    float invA[4], invB[4];
    #pragma unroll
    for (int r = 0; r < 4; ++r) {
        invA[r] = 1.f / laccA[r];
        invB[r] = 1.f / laccB[r];
    }

    u16* xoA = Xa + (size_t)(b * S_ + qt * 128 + w * 32 + grp * 4) * D_ + h * DK_;
    u16* xoB = xoA + (size_t)16 * D_;
    #pragma unroll
    for (int r = 0; r < 4; ++r)
        #pragma unroll
        for (int nt = 0; nt < 4; ++nt) {
            xoA[(size_t)r * D_ + nt * 16 + colL] = f_to_bf16(oA[nt][r] * invA[r]);
            xoB[(size_t)r * D_ + nt * 16 + colL] = f_to_bf16(oB[nt][r] * invB[r]);
        }
}

extern "C" void kernel_launch(void* const* d_in, const int* in_sizes, int n_in,
                              void* d_out, int out_size, void* d_ws, size_t ws_size,
                              hipStream_t stream) {
    const float* q    = (const float*)d_in[0];
    const float* k    = (const float*)d_in[1];
    const float* v    = (const float*)d_in[2];
    const int*   mask = (const int*)d_in[3];
    const float* Wq   = (const float*)d_in[4];
    const float* Wk   = (const float*)d_in[5];
    const float* Wv   = (const float*)d_in[6];
    const float* Wo   = (const float*)d_in[7];
    float* out = (float*)d_out;

    const int NQ = B_ * S_ * D_;   // 4,194,304
    const int NW = D_ * D_;        // 1,048,576

    u16* qb  = (u16*)d_ws;
    u16* kb  = qb  + NQ;
    u16* vb  = kb  + NQ;
    u16* Wqt = vb  + NQ;
    u16* Wkt = Wqt + NW;
    u16* Wvt = Wkt + NW;
    u16* Wot = Wvt + NW;
    u16* Qp  = Wot + NW;
    u16* Kp  = Qp  + NQ;
    u16* Vt  = Kp  + NQ;   // [B][H][DK][tau(S)]
    u16* Xa  = Vt  + NQ;
    u64* mpk = (u64*)(Xa + NQ);    // 1 MB packed mask

    dim3 cblk(256);
    prep<<<14336, cblk, 0, stream>>>(q, k, v, mask, Wq, Wk, Wv, Wo,
                                     qb, kb, vb, Wqt, Wkt, Wvt, Wot, mpk);

    const int M = B_ * S_;  // 4096
    gemm_qkv<<<dim3(M / 128, D_ / 128, 3), cblk, 0, stream>>>(qb, kb, vb, Wqt, Wkt, Wvt, Qp, Kp, Vt);

    attn128<<<B_ * H_ * (S_ / 128), cblk, 0, stream>>>(Qp, Kp, Vt, mpk, Xa);

    gemm_out<<<dim3(M / 64, D_ / 128), cblk, 0, stream>>>(Xa, Wot, out);
}